// Round 10
// baseline (803.908 us; speedup 1.0000x reference)
//
#include <hip/hip_runtime.h>
#include <hip/hip_bf16.h>
#include <math.h>

#define N_NODES 20000
#define N_EDGES 160000
#define NGRAPH  128
#define NLAYER  3
#define M_PAD   20096   // 314 * 64

typedef short bf16x8 __attribute__((ext_vector_type(8)));
typedef float f32x4  __attribute__((ext_vector_type(4)));

__device__ __forceinline__ ushort f2bf(float x) {
    __hip_bfloat16 h = __float2bfloat16(x);
    return *(ushort*)&h;
}
__device__ __forceinline__ float bf2f(ushort u) {
    __hip_bfloat16 h = *(__hip_bfloat16*)&u;
    return __bfloat162float(h);
}

__device__ __forceinline__ void gload16(const void* g, void* l) {
    __builtin_amdgcn_global_load_lds(
        (const __attribute__((address_space(1))) void*)g,
        (__attribute__((address_space(3))) void*)l, 16, 0, 0);
}

// ---------------------------------------------------------------- node init
__global__ __launch_bounds__(256) void k_node_init(
    const int* __restrict__ xt, const float* __restrict__ pos,
    const int* __restrict__ batch, const float* __restrict__ ctx,
    const float* __restrict__ embW, const float* __restrict__ embb,
    float* __restrict__ x)
{
    int n = blockIdx.x;
    int c = threadIdx.x;
    float v;
    if (c < 80) {
        v = embW[xt[n] * 80 + c] + embb[c];
    } else if (c < 128) {
        int j = c - 80;
        int coord = j >> 4;      // 0..2
        int k = j & 15;          // 0..15
        float p = pos[n * 3 + coord];
        int i = (k < 8) ? k : (k - 8);
        float factor = -logf(10000.0f) / 24.0f;   // half = 24
        float d = expf(factor * (float)i);
        float s = p * d;
        v = (k < 8) ? sinf(s) : cosf(s);
    } else {
        v = ctx[batch[n] * 128 + (c - 128)];
    }
    x[n * 256 + c] = v;
}

// ---------------------------------------------------------------- W prep
// Bt[c][kap] = W[(kap&255)*1024 + (kap>>8)*256 + c], split hi/lo bf16,
// stored row-swizzled: pos = c*1024 + (kap ^ ((c&3)<<3))
__global__ __launch_bounds__(256) void k_prepW(
    const float* __restrict__ W, ushort* __restrict__ Bthi, ushort* __restrict__ Btlo)
{
    int idx = blockIdx.x * 256 + threadIdx.x;    // 262144 total
    int c   = idx & 255;
    int kap = idx >> 8;                          // 0..1023
    int k = kap & 255, h = kap >> 8;
    float w = W[(size_t)k * 1024 + h * 256 + c];
    ushort hi = f2bf(w);
    ushort lo = f2bf(w - bf2f(hi));
    int pos = c * 1024 + (kap ^ ((c & 3) << 3));
    Bthi[pos] = hi;
    Btlo[pos] = lo;
}

// ---------------------------------------------------------------- MFMA GEMM
// xc[M,256] = 0.25 * A[M,1024] @ B'[1024,256] + convb
// Split product: A@B ~= Ahi@Bhi + Ahi@Blo + Alo@Bhi  (f32-level accuracy).
// 64x128 block, 4 waves (2x2), BK=32, mfma_f32_16x16x32_bf16.
// T3/T4: 3-buffer LDS ring, 2-ahead prefetch, counted vmcnt(6) (never 0
// mid-loop), raw s_barrier. Per-iter: vmcnt(tile t landed) -> barrier
// (all waves done reading t-1) -> stage(t+2) into buf[(t-1)%3] -> compute t.
__global__ __launch_bounds__(256) void k_gemm_mfma(
    const ushort* __restrict__ Ahi, const ushort* __restrict__ Alo,
    const ushort* __restrict__ Bhi, const ushort* __restrict__ Blo,
    const float* __restrict__ convb, float* __restrict__ xc, int M)
{
    __shared__ ushort sAh[3][64 * 32];
    __shared__ ushort sAl[3][64 * 32];
    __shared__ ushort sBh[3][128 * 32];
    __shared__ ushort sBl[3][128 * 32];

    const int tid  = threadIdx.x;
    const int lane = tid & 63;
    const int wv   = tid >> 6;
    const int wr   = (wv >> 1) * 32;     // 0 / 32
    const int wc   = (wv & 1) * 64;      // 0 / 64
    const int bm   = blockIdx.y * 64;
    const int bn   = blockIdx.x * 128;
    const int r15  = lane & 15;
    const int g    = lane >> 4;          // 0..3 (k-chunk group)

    const int  arow = tid >> 2, ach = tid & 3;
    const uint la   = (uint)tid * 16;

    // stage tile t (6 global_load_lds per thread -> vmcnt unit = 6)
    auto stage = [&](int t) {
        int buf = t % 3;
        int kt  = t * 32;
        size_t ga = (size_t)(bm + arow) * 1024 + kt + ach * 8;
        gload16(&Ahi[ga], (char*)sAh[buf] + la);
        gload16(&Alo[ga], (char*)sAl[buf] + la);
#pragma unroll
        for (int call = 0; call < 2; ++call) {
            int i   = call * 256 + tid;
            int row = i >> 2, ch = i & 3;
            size_t gb = (size_t)(bn + row) * 1024 + kt + ch * 8;
            uint lb = (uint)i * 16;
            gload16(&Bhi[gb], (char*)sBh[buf] + lb);
            gload16(&Blo[gb], (char*)sBl[buf] + lb);
        }
    };

    f32x4 acc[2][4] = {};

    stage(0);
    stage(1);

    for (int t = 0; t < 32; ++t) {
        if (t < 31) asm volatile("s_waitcnt vmcnt(6)" ::: "memory");
        else        asm volatile("s_waitcnt vmcnt(0)" ::: "memory");
        __builtin_amdgcn_s_barrier();
        __builtin_amdgcn_sched_barrier(0);
        if (t + 2 < 32) stage(t + 2);

        const int buf = t % 3;
        bf16x8 afh[2], afl[2], bfh[4], bfl[4];
#pragma unroll
        for (int f = 0; f < 2; ++f) {
            int rowA = wr + f * 16 + r15;
            int offA = rowA * 64 + ((g << 4) ^ ((rowA & 3) << 4));
            afh[f] = *(const bf16x8*)((const char*)sAh[buf] + offA);
            afl[f] = *(const bf16x8*)((const char*)sAl[buf] + offA);
        }
#pragma unroll
        for (int f = 0; f < 4; ++f) {
            int rowB = wc + f * 16 + r15;
            int offB = rowB * 64 + ((g << 4) ^ ((rowB & 3) << 4));
            bfh[f] = *(const bf16x8*)((const char*)sBh[buf] + offB);
            bfl[f] = *(const bf16x8*)((const char*)sBl[buf] + offB);
        }
#pragma unroll
        for (int fi = 0; fi < 2; ++fi)
#pragma unroll
            for (int fj = 0; fj < 4; ++fj) {
                acc[fi][fj] = __builtin_amdgcn_mfma_f32_16x16x32_bf16(
                    afh[fi], bfh[fj], acc[fi][fj], 0, 0, 0);
                acc[fi][fj] = __builtin_amdgcn_mfma_f32_16x16x32_bf16(
                    afh[fi], bfl[fj], acc[fi][fj], 0, 0, 0);
                acc[fi][fj] = __builtin_amdgcn_mfma_f32_16x16x32_bf16(
                    afl[fi], bfh[fj], acc[fi][fj], 0, 0, 0);
            }
        // no trailing barrier: next iter's vmcnt+barrier provides the sync
    }

    // epilogue: D layout col=lane&15, row=(lane>>4)*4+reg  [m89-verified]
#pragma unroll
    for (int fi = 0; fi < 2; ++fi) {
#pragma unroll
        for (int fj = 0; fj < 4; ++fj) {
#pragma unroll
            for (int r = 0; r < 4; ++r) {
                int row = bm + wr + fi * 16 + g * 4 + r;
                int col = bn + wc + fj * 16 + r15;
                if (row < M)
                    xc[(size_t)row * 256 + col] = 0.25f * acc[fi][fj][r] + convb[col];
            }
        }
    }
}

// ---------------------------------------------------------------- u-vectors
__global__ __launch_bounds__(256) void k_uvec(
    const float* __restrict__ W, const float* __restrict__ aS,
    const float* __restrict__ aD, float* __restrict__ uS, float* __restrict__ uD)
{
    int wid  = blockIdx.x * 4 + (threadIdx.x >> 6);  // 0..1023
    int lane = threadIdx.x & 63;
    int h = wid >> 8;
    int k = wid & 255;
    float4 w = *(const float4*)&W[(size_t)k * 1024 + h * 256 + lane * 4];
    float4 s = *(const float4*)&aS[h * 256 + lane * 4];
    float4 d = *(const float4*)&aD[h * 256 + lane * 4];
    float ps = w.x * s.x + w.y * s.y + w.z * s.z + w.w * s.w;
    float pd = w.x * d.x + w.y * d.y + w.z * d.z + w.w * d.w;
    for (int o = 32; o; o >>= 1) {
        ps += __shfl_down(ps, o, 64);
        pd += __shfl_down(pd, o, 64);
    }
    if (lane == 0) { uS[h * 256 + k] = ps; uD[h * 256 + k] = pd; }
}

// ---------------------------------------------------------------- attn dots
__global__ __launch_bounds__(256) void k_attn_dots_x(
    const float* __restrict__ x, const float* __restrict__ uS,
    const float* __restrict__ uD, float* __restrict__ asrc, float* __restrict__ adst)
{
    int n = blockIdx.x;
    int h = threadIdx.x >> 6;
    int lane = threadIdx.x & 63;
    float4 xv = *(const float4*)&x[(size_t)n * 256 + lane * 4];
    float4 sv = *(const float4*)&uS[h * 256 + lane * 4];
    float4 dv = *(const float4*)&uD[h * 256 + lane * 4];
    float ps = xv.x * sv.x + xv.y * sv.y + xv.z * sv.z + xv.w * sv.w;
    float pd = xv.x * dv.x + xv.y * dv.y + xv.z * dv.z + xv.w * dv.w;
    for (int o = 32; o; o >>= 1) {
        ps += __shfl_down(ps, o, 64);
        pd += __shfl_down(pd, o, 64);
    }
    if (lane == 0) { asrc[n * 4 + h] = ps; adst[n * 4 + h] = pd; }
}

// ---------------------------------------------------------------- edge M
__global__ void k_edge_M(const float* __restrict__ eW, const float* __restrict__ aE,
                         float* __restrict__ M)
{
    int f = blockIdx.x >> 2, h = blockIdx.x & 3;
    int lane = threadIdx.x;
    float4 w = *(const float4*)&eW[f * 1024 + h * 256 + lane * 4];
    float4 a = *(const float4*)&aE[h * 256 + lane * 4];
    float p = w.x * a.x + w.y * a.y + w.z * a.z + w.w * a.w;
    for (int o = 32; o; o >>= 1) p += __shfl_down(p, o, 64);
    if (lane == 0) M[f * 4 + h] = p;
}

// ---------------------------------------------------------------- edge alpha
// ex written in CSR order (pos[e]) so aggregate reads it sequentially.
// (no max-subtraction: alphas O(0.3) with 0.02-scale weights; exp safe)
__global__ __launch_bounds__(256) void k_edge_alpha(
    const int* __restrict__ src, const int* __restrict__ dst,
    const float* __restrict__ ea, const float* __restrict__ asrc,
    const float* __restrict__ adst, const float* __restrict__ M,
    const int* __restrict__ pos, float* __restrict__ ex)
{
    int e = blockIdx.x * 256 + threadIdx.x;
    if (e >= N_EDGES) return;
    int s = src[e], d = dst[e];
    float as_[4], ad_[4];
    *(float4*)as_ = *(const float4*)&asrc[s * 4];
    *(float4*)ad_ = *(const float4*)&adst[d * 4];
    float f[5];
#pragma unroll
    for (int i = 0; i < 5; ++i) f[i] = ea[e * 5 + i];
    float r[4];
#pragma unroll
    for (int h = 0; h < 4; ++h) {
        float m = f[0]*M[h] + f[1]*M[4+h] + f[2]*M[8+h] + f[3]*M[12+h] + f[4]*M[16+h];
        float al = as_[h] + ad_[h] + m;
        al = (al >= 0.f) ? al : 0.2f * al;
        r[h] = expf(al);
    }
    *(float4*)&ex[(size_t)pos[e] * 4] = *(float4*)r;
}

// ---------------------------------------------------------------- CSR build
__global__ void k_hist(const int* __restrict__ dst, int* __restrict__ deg)
{
    int e = blockIdx.x * 256 + threadIdx.x;
    if (e < N_EDGES) atomicAdd(&deg[dst[e]], 1);
}

#define SCAN_T 1024
__global__ __launch_bounds__(1024) void k_scan(
    const int* __restrict__ deg, int* __restrict__ off, int* __restrict__ cursor)
{
    __shared__ int sums[SCAN_T];
    int t = threadIdx.x;
    const int CHK = (N_NODES + SCAN_T - 1) / SCAN_T;  // 20
    int base = t * CHK;
    int s = 0;
    for (int i = 0; i < CHK; ++i) {
        int idx = base + i;
        if (idx < N_NODES) s += deg[idx];
    }
    sums[t] = s;
    __syncthreads();
    for (int o = 1; o < SCAN_T; o <<= 1) {
        int v = (t >= o) ? sums[t - o] : 0;
        __syncthreads();
        sums[t] += v;
        __syncthreads();
    }
    int run = (t > 0) ? sums[t - 1] : 0;
    for (int i = 0; i < CHK; ++i) {
        int idx = base + i;
        if (idx < N_NODES) {
            off[idx] = run; cursor[idx] = run;
            run += deg[idx];
        }
    }
    if (t == SCAN_T - 1) off[N_NODES] = sums[SCAN_T - 1];
}

// pos[e] = CSR slot of edge e; srcs[slot] = src[e]
__global__ void k_scatter(const int* __restrict__ dst, const int* __restrict__ src,
                          int* __restrict__ cursor, int* __restrict__ pos,
                          int* __restrict__ srcs)
{
    int e = blockIdx.x * 256 + threadIdx.x;
    if (e >= N_EDGES) return;
    int p = atomicAdd(&cursor[dst[e]], 1);
    pos[e] = p;
    srcs[p] = src[e];
}

// ---------------------------------------------------------------- aggregate
// agg[n, h*256+c] = (sum_{e->n} ex[e,h] * x[src_e, c]) / (sum ex[e,h] + eps)
// ex/srcs CSR-ordered; unroll-4 puts 4 independent x-row gathers in flight.
// Output: bf16 hi/lo planes, row-swizzled (kap ^ ((n&3)<<3)) for the GEMM.
__global__ __launch_bounds__(256) void k_aggregate_x(
    const float* __restrict__ x, const float* __restrict__ ex,
    const int* __restrict__ off, const int* __restrict__ srcs,
    ushort* __restrict__ agghi, ushort* __restrict__ agglo)
{
    int n = blockIdx.x;
    int c = threadIdx.x;
    int e0 = off[n], e1 = off[n + 1];
    float a0 = 0.f, a1 = 0.f, a2 = 0.f, a3 = 0.f;
    float d0 = 0.f, d1 = 0.f, d2 = 0.f, d3 = 0.f;
    int e = e0;
    for (; e + 3 < e1; e += 4) {
        float4 w0 = *(const float4*)&ex[(size_t)(e + 0) * 4];
        float4 w1 = *(const float4*)&ex[(size_t)(e + 1) * 4];
        float4 w2 = *(const float4*)&ex[(size_t)(e + 2) * 4];
        float4 w3 = *(const float4*)&ex[(size_t)(e + 3) * 4];
        int s0 = srcs[e + 0], s1 = srcs[e + 1], s2 = srcs[e + 2], s3 = srcs[e + 3];
        float x0 = x[(size_t)s0 * 256 + c];
        float x1 = x[(size_t)s1 * 256 + c];
        float x2 = x[(size_t)s2 * 256 + c];
        float x3 = x[(size_t)s3 * 256 + c];
        a0 += w0.x * x0 + w1.x * x1 + w2.x * x2 + w3.x * x3;
        a1 += w0.y * x0 + w1.y * x1 + w2.y * x2 + w3.y * x3;
        a2 += w0.z * x0 + w1.z * x1 + w2.z * x2 + w3.z * x3;
        a3 += w0.w * x0 + w1.w * x1 + w2.w * x2 + w3.w * x3;
        d0 += w0.x + w1.x + w2.x + w3.x;
        d1 += w0.y + w1.y + w2.y + w3.y;
        d2 += w0.z + w1.z + w2.z + w3.z;
        d3 += w0.w + w1.w + w2.w + w3.w;
    }
    for (; e < e1; ++e) {
        float4 w = *(const float4*)&ex[(size_t)e * 4];
        float xv = x[(size_t)srcs[e] * 256 + c];
        a0 += w.x * xv; a1 += w.y * xv; a2 += w.z * xv; a3 += w.w * xv;
        d0 += w.x; d1 += w.y; d2 += w.z; d3 += w.w;
    }
    float v[4];
    v[0] = a0 / (d0 + 1e-16f);
    v[1] = a1 / (d1 + 1e-16f);
    v[2] = a2 / (d2 + 1e-16f);
    v[3] = a3 / (d3 + 1e-16f);
    int cs = c ^ ((n & 3) << 3);   // swizzle bits 3-4 (within 32-elem window)
    size_t b = (size_t)n * 1024 + cs;
#pragma unroll
    for (int h = 0; h < 4; ++h) {
        ushort hi = f2bf(v[h]);
        ushort lo = f2bf(v[h] - bf2f(hi));
        agghi[b + h * 256] = hi;
        agglo[b + h * 256] = lo;
    }
}

// ---------------------------------------------------------------- batch-norm
__global__ __launch_bounds__(256) void k_bn_reduce(
    const float* __restrict__ xc, float* __restrict__ sums)
{
    int c = threadIdx.x;
    float s = 0.f, q = 0.f;
    for (int n = blockIdx.x; n < N_NODES; n += gridDim.x) {
        float v = xc[n * 256 + c];
        s += v; q += v * v;
    }
    atomicAdd(&sums[c], s);
    atomicAdd(&sums[256 + c], q);
}

__global__ __launch_bounds__(256) void k_bn_apply(
    const float* __restrict__ xc, const float* __restrict__ sums,
    const float* __restrict__ gamma, const float* __restrict__ beta,
    float* __restrict__ x)
{
    int i = blockIdx.x * 256 + threadIdx.x;
    if (i >= N_NODES * 256) return;
    int c = i & 255;
    const float invN = 1.0f / (float)N_NODES;
    float mu  = sums[c] * invN;
    float var = sums[256 + c] * invN - mu * mu;
    float v = (xc[i] - mu) * (1.0f / sqrtf(var + 1e-5f)) * gamma[c] + beta[c];
    float g = 0.5f * v * (1.0f + erff(v * 0.70710678118654752f));  // exact gelu
    x[i] += g;
}

// ---------------------------------------------------------------- pool x
__global__ __launch_bounds__(256) void k_pool_x(
    const float* __restrict__ x, const int* __restrict__ batch,
    float* __restrict__ Xg, float* __restrict__ cnt)
{
    int g = blockIdx.x;
    int c = threadIdx.x;
    int a = 0, b = N_NODES;
    while (a < b) { int m = (a + b) >> 1; if (batch[m] < g) a = m + 1; else b = m; }
    int lo = a;
    b = N_NODES;
    while (a < b) { int m = (a + b) >> 1; if (batch[m] < g + 1) a = m + 1; else b = m; }
    int hi = a;
    float s = 0.f;
    for (int n = lo; n < hi; ++n) s += x[(size_t)n * 256 + c];
    Xg[g * 256 + c] = s;
    if (c == 0) cnt[g] = (float)(hi - lo);
}

// ---------------------------------------------------------------- out GEMV
__global__ __launch_bounds__(256) void k_out_gemv(
    const float* __restrict__ Xg, const float* __restrict__ W,
    const float* __restrict__ b, const float* __restrict__ cnt,
    float* __restrict__ out)
{
    __shared__ float sx[256];
    int g = blockIdx.x;
    int cc = blockIdx.y * 256 + threadIdx.x;
    sx[threadIdx.x] = Xg[g * 256 + threadIdx.x];
    __syncthreads();
    float acc = 0.f;
#pragma unroll 8
    for (int k = 0; k < 256; ++k)
        acc += sx[k] * W[(size_t)k * 1024 + cc];
    out[(size_t)g * 1024 + cc] = acc + cnt[g] * b[cc];
}

// ---------------------------------------------------------------- launch
extern "C" void kernel_launch(void* const* d_in, const int* in_sizes, int n_in,
                              void* d_out, int out_size, void* d_ws, size_t ws_size,
                              hipStream_t stream)
{
    const int*   xt    = (const int*)d_in[0];
    const float* pos   = (const float*)d_in[1];
    const int*   eidx  = (const int*)d_in[2];
    const float* ea    = (const float*)d_in[3];
    const int*   batch = (const int*)d_in[4];
    const float* ctx   = (const float*)d_in[5];
    const float* embW  = (const float*)d_in[6];
    const float* embb  = (const float*)d_in[7];
    const float* linW  = (const float*)d_in[8];
    const float* attS  = (const float*)d_in[9];
    const float* attD  = (const float*)d_in[10];
    const float* edgeW = (const float*)d_in[11];
    const float* attE  = (const float*)d_in[12];
    const float* convb = (const float*)d_in[13];
    const float* gamma = (const float*)d_in[14];
    const float* beta  = (const float*)d_in[15];
    const float* outW  = (const float*)d_in[16];
    const float* outb  = (const float*)d_in[17];
    float* out = (float*)d_out;
    const int* src = eidx;
    const int* dst = eidx + N_EDGES;

    char* p = (char*)d_ws;
    auto alloc = [&](size_t bytes) {
        void* r = (void*)p;
        p += (bytes + 255) & ~(size_t)255;
        return r;
    };
    float*  x     = (float*)alloc((size_t)N_NODES * 256 * 4);
    ushort* agghi = (ushort*)alloc((size_t)M_PAD * 1024 * 2);
    ushort* agglo = (ushort*)alloc((size_t)M_PAD * 1024 * 2);
    ushort* Bthi  = (ushort*)alloc((size_t)256 * 1024 * 2);
    ushort* Btlo  = (ushort*)alloc((size_t)256 * 1024 * 2);
    float*  xc    = (float*)alloc((size_t)N_NODES * 256 * 4);
    float*  asrc  = (float*)alloc((size_t)N_NODES * 4 * 4);
    float*  adst  = (float*)alloc((size_t)N_NODES * 4 * 4);
    float*  ex    = (float*)alloc((size_t)N_EDGES * 4 * 4);
    float*  Mbuf  = (float*)alloc(20 * 4);
    float*  uS    = (float*)alloc(1024 * 4);
    float*  uD    = (float*)alloc(1024 * 4);
    float*  sums  = (float*)alloc(512 * 4);
    float*  Xg    = (float*)alloc((size_t)NGRAPH * 256 * 4);
    float*  cnt   = (float*)alloc((size_t)NGRAPH * 4);
    int*  deg    = (int*)alloc((size_t)N_NODES * 4);
    int*  off    = (int*)alloc((size_t)(N_NODES + 1) * 4);
    int*  cursor = (int*)alloc((size_t)N_NODES * 4);
    int*  posb   = (int*)alloc((size_t)N_EDGES * 4);
    int*  srcs   = (int*)alloc((size_t)N_EDGES * 4);

    // node features + CSR (edge_index is layer-invariant: build once)
    k_node_init<<<N_NODES, 256, 0, stream>>>(xt, pos, batch, ctx, embW, embb, x);
    hipMemsetAsync(deg, 0, (size_t)N_NODES * 4, stream);
    k_hist<<<(N_EDGES + 255) / 256, 256, 0, stream>>>(dst, deg);
    k_scan<<<1, SCAN_T, 0, stream>>>(deg, off, cursor);
    k_scatter<<<(N_EDGES + 255) / 256, 256, 0, stream>>>(dst, src, cursor, posb, srcs);

    dim3 ggrid(2, (M_PAD / 64));   // (2, 314)
    for (int l = 0; l < NLAYER; ++l) {
        const float* W = linW + (size_t)l * 256 * 1024;
        k_uvec<<<256, 256, 0, stream>>>(W, attS + l * 1024, attD + l * 1024, uS, uD);
        k_attn_dots_x<<<N_NODES, 256, 0, stream>>>(x, uS, uD, asrc, adst);
        k_edge_M<<<20, 64, 0, stream>>>(edgeW + l * 5 * 1024, attE + l * 1024, Mbuf);
        k_edge_alpha<<<(N_EDGES + 255) / 256, 256, 0, stream>>>(src, dst, ea, asrc, adst, Mbuf, posb, ex);
        k_aggregate_x<<<N_NODES, 256, 0, stream>>>(x, ex, off, srcs, agghi, agglo);
        k_prepW<<<1024, 256, 0, stream>>>(W, Bthi, Btlo);
        k_gemm_mfma<<<ggrid, 256, 0, stream>>>(agghi, agglo, Bthi, Btlo,
                                               convb + l * 256, xc, N_NODES);
        hipMemsetAsync(sums, 0, 512 * 4, stream);
        k_bn_reduce<<<256, 256, 0, stream>>>(xc, sums);
        k_bn_apply<<<(N_NODES * 256 + 255) / 256, 256, 0, stream>>>(xc, sums, gamma + l * 256, beta + l * 256, x);
    }
    // pool-before-projection: Xg = segsum(x), out = Xg @ out_W + cnt*out_b
    k_pool_x<<<NGRAPH, 256, 0, stream>>>(x, batch, Xg, cnt);
    k_out_gemv<<<dim3(NGRAPH, 4), 256, 0, stream>>>(Xg, outW, outb, cnt, out);
}

// Round 12
// 718.718 us; speedup vs baseline: 1.1185x; 1.1185x over previous
//
#include <hip/hip_runtime.h>
#include <hip/hip_bf16.h>
#include <math.h>

#define N_NODES 20000
#define N_EDGES 160000
#define NGRAPH  128
#define NLAYER  3
#define M_PAD   20096   // 628 * 32

typedef short bf16x8 __attribute__((ext_vector_type(8)));
typedef float f32x4  __attribute__((ext_vector_type(4)));

__device__ __forceinline__ ushort f2bf(float x) {
    __hip_bfloat16 h = __float2bfloat16(x);
    return *(ushort*)&h;
}
__device__ __forceinline__ float bf2f(ushort u) {
    __hip_bfloat16 h = *(__hip_bfloat16*)&u;
    return __bfloat162float(h);
}

__device__ __forceinline__ void gload16(const void* g, void* l) {
    __builtin_amdgcn_global_load_lds(
        (const __attribute__((address_space(1))) void*)g,
        (__attribute__((address_space(3))) void*)l, 16, 0, 0);
}

// ---------------------------------------------------------------- node init
__global__ __launch_bounds__(256) void k_node_init(
    const int* __restrict__ xt, const float* __restrict__ pos,
    const int* __restrict__ batch, const float* __restrict__ ctx,
    const float* __restrict__ embW, const float* __restrict__ embb,
    float* __restrict__ x)
{
    int n = blockIdx.x;
    int c = threadIdx.x;
    float v;
    if (c < 80) {
        v = embW[xt[n] * 80 + c] + embb[c];
    } else if (c < 128) {
        int j = c - 80;
        int coord = j >> 4;      // 0..2
        int k = j & 15;          // 0..15
        float p = pos[n * 3 + coord];
        int i = (k < 8) ? k : (k - 8);
        float factor = -logf(10000.0f) / 24.0f;   // half = 24
        float d = expf(factor * (float)i);
        float s = p * d;
        v = (k < 8) ? sinf(s) : cosf(s);
    } else {
        v = ctx[batch[n] * 128 + (c - 128)];
    }
    x[n * 256 + c] = v;
}

// ---------------------------------------------------------------- W prep
// All 3 layers in one launch. Bt[l][c][kap] = W_l[(kap&255)*1024+(kap>>8)*256+c],
// split hi/lo bf16, row-swizzled: pos = c*1024 + (kap ^ ((c&3)<<3))
__global__ __launch_bounds__(256) void k_prepW(
    const float* __restrict__ linW, ushort* __restrict__ Bthi, ushort* __restrict__ Btlo)
{
    int l   = blockIdx.y;
    int idx = blockIdx.x * 256 + threadIdx.x;    // 262144 per layer
    int c   = idx & 255;
    int kap = idx >> 8;                          // 0..1023
    int k = kap & 255, h = kap >> 8;
    float w = linW[(size_t)l * 262144 + (size_t)k * 1024 + h * 256 + c];
    ushort hi = f2bf(w);
    ushort lo = f2bf(w - bf2f(hi));
    size_t pos = (size_t)l * 262144 + c * 1024 + (kap ^ ((c & 3) << 3));
    Bthi[pos] = hi;
    Btlo[pos] = lo;
}

// ---------------------------------------------------------------- MFMA GEMM
// xc[M,256] = 0.25 * A[M,1024] @ B'[1024,256] + convb
// Split product: A@B ~= Ahi@Bhi + Ahi@Blo + Alo@Bhi  (f32-level accuracy).
// 32x128 block (1256 blocks -> ~4.9/CU: TLP hides the per-iter barrier
// drain; R10's in-wave vmcnt pipeline regressed — compiler re-inserts its
// own vmcnt(0)), 4 waves (2x2), 16x64/wave, BK=32, mfma_f32_16x16x32_bf16.
__global__ __launch_bounds__(256) void k_gemm_mfma(
    const ushort* __restrict__ Ahi, const ushort* __restrict__ Alo,
    const ushort* __restrict__ Bhi, const ushort* __restrict__ Blo,
    const float* __restrict__ convb, float* __restrict__ xc, int M)
{
    __shared__ ushort sAh[32 * 32];
    __shared__ ushort sAl[32 * 32];
    __shared__ ushort sBh[128 * 32];
    __shared__ ushort sBl[128 * 32];

    const int tid  = threadIdx.x;
    const int lane = tid & 63;
    const int wv   = tid >> 6;
    const int wr   = (wv >> 1) * 16;     // 0 / 16
    const int wc   = (wv & 1) * 64;      // 0 / 64
    const int bm   = blockIdx.y * 32;
    const int bn   = blockIdx.x * 128;
    const int r15  = lane & 15;
    const int g    = lane >> 4;          // 0..3 (k-chunk group)

    f32x4 acc[4] = {};

    for (int kt = 0; kt < 1024; kt += 32) {
        {   // A tile: 32 rows x 32 k = 128 chunks/plane; tid<128 hi, else lo
            int i = tid & 127;
            int row = i >> 2, ch = i & 3;
            size_t ga = (size_t)(bm + row) * 1024 + kt + ch * 8;
            uint la = (uint)i * 16;
            if (tid < 128) gload16(&Ahi[ga], (char*)sAh + la);
            else           gload16(&Alo[ga], (char*)sAl + la);
        }
#pragma unroll
        for (int call = 0; call < 2; ++call) {   // Bhi: 512 chunks
            int i = call * 256 + tid;
            int row = i >> 2, ch = i & 3;
            size_t gb = (size_t)(bn + row) * 1024 + kt + ch * 8;
            gload16(&Bhi[gb], (char*)sBh + (uint)i * 16);
        }
#pragma unroll
        for (int call = 0; call < 2; ++call) {   // Blo: 512 chunks
            int i = call * 256 + tid;
            int row = i >> 2, ch = i & 3;
            size_t gb = (size_t)(bn + row) * 1024 + kt + ch * 8;
            gload16(&Blo[gb], (char*)sBl + (uint)i * 16);
        }
        __syncthreads();

        bf16x8 afh, afl, bfh[4], bfl[4];
        {
            int rowA = wr + r15;
            int offA = rowA * 64 + ((g << 4) ^ ((rowA & 3) << 4));
            afh = *(const bf16x8*)((const char*)sAh + offA);
            afl = *(const bf16x8*)((const char*)sAl + offA);
        }
#pragma unroll
        for (int f = 0; f < 4; ++f) {
            int rowB = wc + f * 16 + r15;
            int offB = rowB * 64 + ((g << 4) ^ ((rowB & 3) << 4));
            bfh[f] = *(const bf16x8*)((const char*)sBh + offB);
            bfl[f] = *(const bf16x8*)((const char*)sBl + offB);
        }
#pragma unroll
        for (int fj = 0; fj < 4; ++fj) {
            acc[fj] = __builtin_amdgcn_mfma_f32_16x16x32_bf16(afh, bfh[fj], acc[fj], 0, 0, 0);
            acc[fj] = __builtin_amdgcn_mfma_f32_16x16x32_bf16(afh, bfl[fj], acc[fj], 0, 0, 0);
            acc[fj] = __builtin_amdgcn_mfma_f32_16x16x32_bf16(afl, bfh[fj], acc[fj], 0, 0, 0);
        }
        __syncthreads();
    }

    // epilogue: D layout col=lane&15, row=(lane>>4)*4+reg  [m89-verified]
#pragma unroll
    for (int fj = 0; fj < 4; ++fj) {
#pragma unroll
        for (int r = 0; r < 4; ++r) {
            int row = bm + wr + g * 4 + r;
            int col = bn + wc + fj * 16 + r15;
            if (row < M)
                xc[(size_t)row * 256 + col] = 0.25f * acc[fj][r] + convb[col];
        }
    }
}

// ---------------------------------------------------------------- u-vectors
__global__ __launch_bounds__(256) void k_uvec(
    const float* __restrict__ W, const float* __restrict__ aS,
    const float* __restrict__ aD, float* __restrict__ uS, float* __restrict__ uD)
{
    int wid  = blockIdx.x * 4 + (threadIdx.x >> 6);  // 0..1023
    int lane = threadIdx.x & 63;
    int h = wid >> 8;
    int k = wid & 255;
    float4 w = *(const float4*)&W[(size_t)k * 1024 + h * 256 + lane * 4];
    float4 s = *(const float4*)&aS[h * 256 + lane * 4];
    float4 d = *(const float4*)&aD[h * 256 + lane * 4];
    float ps = w.x * s.x + w.y * s.y + w.z * s.z + w.w * s.w;
    float pd = w.x * d.x + w.y * d.y + w.z * d.z + w.w * d.w;
    for (int o = 32; o; o >>= 1) {
        ps += __shfl_down(ps, o, 64);
        pd += __shfl_down(pd, o, 64);
    }
    if (lane == 0) { uS[h * 256 + k] = ps; uD[h * 256 + k] = pd; }
}

// ---------------------------------------------------------------- attn dots
__global__ __launch_bounds__(256) void k_attn_dots_x(
    const float* __restrict__ x, const float* __restrict__ uS,
    const float* __restrict__ uD, float* __restrict__ asrc, float* __restrict__ adst)
{
    int n = blockIdx.x;
    int h = threadIdx.x >> 6;
    int lane = threadIdx.x & 63;
    float4 xv = *(const float4*)&x[(size_t)n * 256 + lane * 4];
    float4 sv = *(const float4*)&uS[h * 256 + lane * 4];
    float4 dv = *(const float4*)&uD[h * 256 + lane * 4];
    float ps = xv.x * sv.x + xv.y * sv.y + xv.z * sv.z + xv.w * sv.w;
    float pd = xv.x * dv.x + xv.y * dv.y + xv.z * dv.z + xv.w * dv.w;
    for (int o = 32; o; o >>= 1) {
        ps += __shfl_down(ps, o, 64);
        pd += __shfl_down(pd, o, 64);
    }
    if (lane == 0) { asrc[n * 4 + h] = ps; adst[n * 4 + h] = pd; }
}

// ---------------------------------------------------------------- edge M
__global__ void k_edge_M(const float* __restrict__ eW, const float* __restrict__ aE,
                         float* __restrict__ M)
{
    int f = blockIdx.x >> 2, h = blockIdx.x & 3;
    int lane = threadIdx.x;
    float4 w = *(const float4*)&eW[f * 1024 + h * 256 + lane * 4];
    float4 a = *(const float4*)&aE[h * 256 + lane * 4];
    float p = w.x * a.x + w.y * a.y + w.z * a.z + w.w * a.w;
    for (int o = 32; o; o >>= 1) p += __shfl_down(p, o, 64);
    if (lane == 0) M[f * 4 + h] = p;
}

// ---------------------------------------------------------------- edge alpha
// ex written in CSR order (pos[e]) so aggregate reads it sequentially.
// (no max-subtraction: alphas O(0.3) with 0.02-scale weights; exp safe)
__global__ __launch_bounds__(256) void k_edge_alpha(
    const int* __restrict__ src, const int* __restrict__ dst,
    const float* __restrict__ ea, const float* __restrict__ asrc,
    const float* __restrict__ adst, const float* __restrict__ M,
    const int* __restrict__ pos, float* __restrict__ ex)
{
    int e = blockIdx.x * 256 + threadIdx.x;
    if (e >= N_EDGES) return;
    int s = src[e], d = dst[e];
    float as_[4], ad_[4];
    *(float4*)as_ = *(const float4*)&asrc[s * 4];
    *(float4*)ad_ = *(const float4*)&adst[d * 4];
    float f[5];
#pragma unroll
    for (int i = 0; i < 5; ++i) f[i] = ea[e * 5 + i];
    float r[4];
#pragma unroll
    for (int h = 0; h < 4; ++h) {
        float m = f[0]*M[h] + f[1]*M[4+h] + f[2]*M[8+h] + f[3]*M[12+h] + f[4]*M[16+h];
        float al = as_[h] + ad_[h] + m;
        al = (al >= 0.f) ? al : 0.2f * al;
        r[h] = expf(al);
    }
    *(float4*)&ex[(size_t)pos[e] * 4] = *(float4*)r;
}

// ---------------------------------------------------------------- CSR build
__global__ void k_hist(const int* __restrict__ dst, int* __restrict__ deg)
{
    int e = blockIdx.x * 256 + threadIdx.x;
    if (e < N_EDGES) atomicAdd(&deg[dst[e]], 1);
}

#define SCAN_T 1024
__global__ __launch_bounds__(1024) void k_scan(
    const int* __restrict__ deg, int* __restrict__ off, int* __restrict__ cursor)
{
    __shared__ int sums[SCAN_T];
    int t = threadIdx.x;
    const int CHK = (N_NODES + SCAN_T - 1) / SCAN_T;  // 20
    int base = t * CHK;
    int s = 0;
    for (int i = 0; i < CHK; ++i) {
        int idx = base + i;
        if (idx < N_NODES) s += deg[idx];
    }
    sums[t] = s;
    __syncthreads();
    for (int o = 1; o < SCAN_T; o <<= 1) {
        int v = (t >= o) ? sums[t - o] : 0;
        __syncthreads();
        sums[t] += v;
        __syncthreads();
    }
    int run = (t > 0) ? sums[t - 1] : 0;
    for (int i = 0; i < CHK; ++i) {
        int idx = base + i;
        if (idx < N_NODES) {
            off[idx] = run; cursor[idx] = run;
            run += deg[idx];
        }
    }
    if (t == SCAN_T - 1) off[N_NODES] = sums[SCAN_T - 1];
}

// pos[e] = CSR slot of edge e; srcs[slot] = src[e]
__global__ void k_scatter(const int* __restrict__ dst, const int* __restrict__ src,
                          int* __restrict__ cursor, int* __restrict__ pos,
                          int* __restrict__ srcs)
{
    int e = blockIdx.x * 256 + threadIdx.x;
    if (e >= N_EDGES) return;
    int p = atomicAdd(&cursor[dst[e]], 1);
    pos[e] = p;
    srcs[p] = src[e];
}

// ---------------------------------------------------------------- aggregate
// agg[n, h*256+c] = (sum_{e->n} ex[e,h] * x[src_e, c]) / (sum ex[e,h] + eps)
// ex/srcs CSR-ordered; unroll-4 puts 4 independent x-row gathers in flight.
// Output: bf16 hi/lo planes, row-swizzled (kap ^ ((n&3)<<3)) for the GEMM.
__global__ __launch_bounds__(256) void k_aggregate_x(
    const float* __restrict__ x, const float* __restrict__ ex,
    const int* __restrict__ off, const int* __restrict__ srcs,
    ushort* __restrict__ agghi, ushort* __restrict__ agglo)
{
    int n = blockIdx.x;
    int c = threadIdx.x;
    int e0 = off[n], e1 = off[n + 1];
    float a0 = 0.f, a1 = 0.f, a2 = 0.f, a3 = 0.f;
    float d0 = 0.f, d1 = 0.f, d2 = 0.f, d3 = 0.f;
    int e = e0;
    for (; e + 3 < e1; e += 4) {
        float4 w0 = *(const float4*)&ex[(size_t)(e + 0) * 4];
        float4 w1 = *(const float4*)&ex[(size_t)(e + 1) * 4];
        float4 w2 = *(const float4*)&ex[(size_t)(e + 2) * 4];
        float4 w3 = *(const float4*)&ex[(size_t)(e + 3) * 4];
        int s0 = srcs[e + 0], s1 = srcs[e + 1], s2 = srcs[e + 2], s3 = srcs[e + 3];
        float x0 = x[(size_t)s0 * 256 + c];
        float x1 = x[(size_t)s1 * 256 + c];
        float x2 = x[(size_t)s2 * 256 + c];
        float x3 = x[(size_t)s3 * 256 + c];
        a0 += w0.x * x0 + w1.x * x1 + w2.x * x2 + w3.x * x3;
        a1 += w0.y * x0 + w1.y * x1 + w2.y * x2 + w3.y * x3;
        a2 += w0.z * x0 + w1.z * x1 + w2.z * x2 + w3.z * x3;
        a3 += w0.w * x0 + w1.w * x1 + w2.w * x2 + w3.w * x3;
        d0 += w0.x + w1.x + w2.x + w3.x;
        d1 += w0.y + w1.y + w2.y + w3.y;
        d2 += w0.z + w1.z + w2.z + w3.z;
        d3 += w0.w + w1.w + w2.w + w3.w;
    }
    for (; e < e1; ++e) {
        float4 w = *(const float4*)&ex[(size_t)e * 4];
        float xv = x[(size_t)srcs[e] * 256 + c];
        a0 += w.x * xv; a1 += w.y * xv; a2 += w.z * xv; a3 += w.w * xv;
        d0 += w.x; d1 += w.y; d2 += w.z; d3 += w.w;
    }
    float v[4];
    v[0] = a0 / (d0 + 1e-16f);
    v[1] = a1 / (d1 + 1e-16f);
    v[2] = a2 / (d2 + 1e-16f);
    v[3] = a3 / (d3 + 1e-16f);
    int cs = c ^ ((n & 3) << 3);   // swizzle bits 3-4 (within 32-elem window)
    size_t b = (size_t)n * 1024 + cs;
#pragma unroll
    for (int h = 0; h < 4; ++h) {
        ushort hi = f2bf(v[h]);
        ushort lo = f2bf(v[h] - bf2f(hi));
        agghi[b + h * 256] = hi;
        agglo[b + h * 256] = lo;
    }
}

// ---------------------------------------------------------------- batch-norm
__global__ __launch_bounds__(256) void k_bn_reduce(
    const float* __restrict__ xc, float* __restrict__ sums)
{
    int c = threadIdx.x;
    float s = 0.f, q = 0.f;
    for (int n = blockIdx.x; n < N_NODES; n += gridDim.x) {
        float v = xc[n * 256 + c];
        s += v; q += v * v;
    }
    atomicAdd(&sums[c], s);
    atomicAdd(&sums[256 + c], q);
}

__global__ __launch_bounds__(256) void k_bn_apply(
    const float* __restrict__ xc, const float* __restrict__ sums,
    const float* __restrict__ gamma, const float* __restrict__ beta,
    float* __restrict__ x)
{
    int i = blockIdx.x * 256 + threadIdx.x;
    if (i >= N_NODES * 256) return;
    int c = i & 255;
    const float invN = 1.0f / (float)N_NODES;
    float mu  = sums[c] * invN;
    float var = sums[256 + c] * invN - mu * mu;
    float v = (xc[i] - mu) * (1.0f / sqrtf(var + 1e-5f)) * gamma[c] + beta[c];
    float g = 0.5f * v * (1.0f + erff(v * 0.70710678118654752f));  // exact gelu
    x[i] += g;
}

// ---------------------------------------------------------------- pool x
__global__ __launch_bounds__(256) void k_pool_x(
    const float* __restrict__ x, const int* __restrict__ batch,
    float* __restrict__ Xg, float* __restrict__ cnt)
{
    int g = blockIdx.x;
    int c = threadIdx.x;
    int a = 0, b = N_NODES;
    while (a < b) { int m = (a + b) >> 1; if (batch[m] < g) a = m + 1; else b = m; }
    int lo = a;
    b = N_NODES;
    while (a < b) { int m = (a + b) >> 1; if (batch[m] < g + 1) a = m + 1; else b = m; }
    int hi = a;
    float s = 0.f;
    for (int n = lo; n < hi; ++n) s += x[(size_t)n * 256 + c];
    Xg[g * 256 + c] = s;
    if (c == 0) cnt[g] = (float)(hi - lo);
}

// ---------------------------------------------------------------- out GEMV
__global__ __launch_bounds__(256) void k_out_gemv(
    const float* __restrict__ Xg, const float* __restrict__ W,
    const float* __restrict__ b, const float* __restrict__ cnt,
    float* __restrict__ out)
{
    __shared__ float sx[256];
    int g = blockIdx.x;
    int cc = blockIdx.y * 256 + threadIdx.x;
    sx[threadIdx.x] = Xg[g * 256 + threadIdx.x];
    __syncthreads();
    float acc = 0.f;
#pragma unroll 8
    for (int k = 0; k < 256; ++k)
        acc += sx[k] * W[(size_t)k * 1024 + cc];
    out[(size_t)g * 1024 + cc] = acc + cnt[g] * b[cc];
}

// ---------------------------------------------------------------- launch
extern "C" void kernel_launch(void* const* d_in, const int* in_sizes, int n_in,
                              void* d_out, int out_size, void* d_ws, size_t ws_size,
                              hipStream_t stream)
{
    const int*   xt    = (const int*)d_in[0];
    const float* pos   = (const float*)d_in[1];
    const int*   eidx  = (const int*)d_in[2];
    const float* ea    = (const float*)d_in[3];
    const int*   batch = (const int*)d_in[4];
    const float* ctx   = (const float*)d_in[5];
    const float* embW  = (const float*)d_in[6];
    const float* embb  = (const float*)d_in[7];
    const float* linW  = (const float*)d_in[8];
    const float* attS  = (const float*)d_in[9];
    const float* attD  = (const float*)d_in[10];
    const float* edgeW = (const float*)d_in[11];
    const float* attE  = (const float*)d_in[12];
    const float* convb = (const float*)d_in[13];
    const float* gamma = (const float*)d_in[14];
    const float* beta  = (const float*)d_in[15];
    const float* outW  = (const float*)d_in[16];
    const float* outb  = (const float*)d_in[17];
    float* out = (float*)d_out;
    const int* src = eidx;
    const int* dst = eidx + N_EDGES;

    char* p = (char*)d_ws;
    auto alloc = [&](size_t bytes) {
        void* r = (void*)p;
        p += (bytes + 255) & ~(size_t)255;
        return r;
    };
    float*  x     = (float*)alloc((size_t)N_NODES * 256 * 4);
    ushort* agghi = (ushort*)alloc((size_t)M_PAD * 1024 * 2);
    ushort* agglo = (ushort*)alloc((size_t)M_PAD * 1024 * 2);
    ushort* Bthi  = (ushort*)alloc((size_t)NLAYER * 256 * 1024 * 2);
    ushort* Btlo  = (ushort*)alloc((size_t)NLAYER * 256 * 1024 * 2);
    float*  xc    = (float*)alloc((size_t)N_NODES * 256 * 4);
    float*  asrc  = (float*)alloc((size_t)N_NODES * 4 * 4);
    float*  adst  = (float*)alloc((size_t)N_NODES * 4 * 4);
    float*  ex    = (float*)alloc((size_t)N_EDGES * 4 * 4);
    float*  Mbuf  = (float*)alloc(20 * 4);
    float*  uS    = (float*)alloc(1024 * 4);
    float*  uD    = (float*)alloc(1024 * 4);
    float*  sums  = (float*)alloc(512 * 4);
    float*  Xg    = (float*)alloc((size_t)NGRAPH * 256 * 4);
    float*  cnt   = (float*)alloc((size_t)NGRAPH * 4);
    int*  deg    = (int*)alloc((size_t)N_NODES * 4);
    int*  off    = (int*)alloc((size_t)(N_NODES + 1) * 4);
    int*  cursor = (int*)alloc((size_t)N_NODES * 4);
    int*  posb   = (int*)alloc((size_t)N_EDGES * 4);
    int*  srcs   = (int*)alloc((size_t)N_EDGES * 4);

    // node features + CSR (edge_index is layer-invariant: build once)
    k_node_init<<<N_NODES, 256, 0, stream>>>(xt, pos, batch, ctx, embW, embb, x);
    hipMemsetAsync(deg, 0, (size_t)N_NODES * 4, stream);
    k_hist<<<(N_EDGES + 255) / 256, 256, 0, stream>>>(dst, deg);
    k_scan<<<1, SCAN_T, 0, stream>>>(deg, off, cursor);
    k_scatter<<<(N_EDGES + 255) / 256, 256, 0, stream>>>(dst, src, cursor, posb, srcs);
    k_prepW<<<dim3(1024, NLAYER), 256, 0, stream>>>(linW, Bthi, Btlo);

    dim3 ggrid(2, M_PAD / 32);   // (2, 628)
    for (int l = 0; l < NLAYER; ++l) {
        const float* W = linW + (size_t)l * 256 * 1024;
        k_uvec<<<256, 256, 0, stream>>>(W, attS + l * 1024, attD + l * 1024, uS, uD);
        k_attn_dots_x<<<N_NODES, 256, 0, stream>>>(x, uS, uD, asrc, adst);
        k_edge_M<<<20, 64, 0, stream>>>(edgeW + l * 5 * 1024, attE + l * 1024, Mbuf);
        k_edge_alpha<<<(N_EDGES + 255) / 256, 256, 0, stream>>>(src, dst, ea, asrc, adst, Mbuf, posb, ex);
        k_aggregate_x<<<N_NODES, 256, 0, stream>>>(x, ex, off, srcs, agghi, agglo);
        k_gemm_mfma<<<ggrid, 256, 0, stream>>>(agghi, agglo,
                                               Bthi + (size_t)l * 262144,
                                               Btlo + (size_t)l * 262144,
                                               convb + l * 256, xc, N_NODES);
        hipMemsetAsync(sums, 0, 512 * 4, stream);
        k_bn_reduce<<<256, 256, 0, stream>>>(xc, sums);
        k_bn_apply<<<(N_NODES * 256 + 255) / 256, 256, 0, stream>>>(xc, sums, gamma + l * 256, beta + l * 256, x);
    }
    // pool-before-projection: Xg = segsum(x), out = Xg @ out_W + cnt*out_b
    k_pool_x<<<NGRAPH, 256, 0, stream>>>(x, batch, Xg, cnt);
    k_out_gemv<<<dim3(NGRAPH, 4), 256, 0, stream>>>(Xg, outW, outb, cnt, out);
}